// Round 8
// baseline (630.250 us; speedup 1.0000x reference)
//
#include <hip/hip_runtime.h>

#define HEADS 3
#define OUT   12
#define HO    36     // HEADS*OUT
#define NMAX  50000
#define EMAX  900000  // E + N self-loops = 850000 for this problem

// Static device-global scratch (no ws_size dependency, no runtime API).
__device__ __align__(16) float g_h  [NMAX * HO];     // transformed features
__device__ __align__(16) float g_als[NMAX * HEADS];  // src attention logits
__device__ __align__(16) float g_ald[NMAX * HEADS];  // dst attention logits
__device__ __align__(16) float g_y  [NMAX * HO];     // layer output
__device__ int g_deg [NMAX];       // in-degree histogram
__device__ int g_off [NMAX];       // CSR row starts (arbitrary order, contiguous per row)
__device__ int g_pos [NMAX];       // scatter cursors
__device__ int g_elist[EMAX];      // CSR: src node per slot
__device__ int g_cursor;           // row allocation cursor
__device__ int g_perm[NMAX];       // nodes sorted by degree (gather load balance)
__device__ int g_dbin[256];        // degree histogram (clamped at 255)
__device__ int g_dscan[256];       // exclusive scan of g_dbin
__device__ int g_dpos[256];        // per-bin cursors

// ---------------- CSR build (rebuilt every call; graph is an input) ------
__global__ void csr_zero_kernel(int N) {
    int t = blockIdx.x * blockDim.x + threadIdx.x;
    if (t < N) { g_deg[t] = 0; g_pos[t] = 0; }
    if (t < 256) { g_dbin[t] = 0; g_dpos[t] = 0; }
    if (t == 0) g_cursor = 0;
}

__global__ void csr_hist_kernel(const int* __restrict__ ei, int E, int N) {
    int t = blockIdx.x * blockDim.x + threadIdx.x;
    if (t >= E + N) return;
    int dst = (t < E) ? ei[E + t] : (t - E);   // explicit edges + self-loops
    atomicAdd(&g_deg[dst], 1);
}

// Scan-free row allocation: rows contiguous but in arbitrary order, which is
// all the gather needs.
__global__ void csr_alloc_kernel(int N) {
    int n = blockIdx.x * blockDim.x + threadIdx.x;
    if (n >= N) return;
    g_off[n] = atomicAdd(&g_cursor, g_deg[n]);
}

__global__ void csr_scatter_kernel(const int* __restrict__ ei, int E, int N) {
    int t = blockIdx.x * blockDim.x + threadIdx.x;
    if (t >= E + N) return;
    int src, dst;
    if (t < E) { src = ei[t]; dst = ei[E + t]; }
    else       { src = dst = t - E; }
    int slot = g_off[dst] + atomicAdd(&g_pos[dst], 1);
    g_elist[slot] = src;
}

// ---------------- degree counting-sort: perm = nodes ordered by degree ---
__global__ void deg_hist_kernel(int N) {
    int n = blockIdx.x * blockDim.x + threadIdx.x;
    if (n >= N) return;
    int b = g_deg[n]; if (b > 255) b = 255;
    atomicAdd(&g_dbin[b], 1);
}

__global__ void deg_scan_kernel() {   // single block, 256 threads
    __shared__ int tmp[256];
    int tid = threadIdx.x;
    int self = g_dbin[tid];
    tmp[tid] = self;
    __syncthreads();
    for (int off = 1; off < 256; off <<= 1) {
        int v = (tid >= off) ? tmp[tid - off] : 0;
        __syncthreads();
        tmp[tid] += v;
        __syncthreads();
    }
    g_dscan[tid] = tmp[tid] - self;   // exclusive
}

__global__ void deg_perm_kernel(int N) {
    int n = blockIdx.x * blockDim.x + threadIdx.x;
    if (n >= N) return;
    int b = g_deg[n]; if (b > 255) b = 255;
    int slot = g_dscan[b] + atomicAdd(&g_dpos[b], 1);
    g_perm[slot] = n;
}

// ---------------- transform (layer 0, F=24): h = x @ W^T, logits --------
__global__ void transform24_kernel(const float* __restrict__ x,
                                   const float* __restrict__ W,     // [36,24]
                                   const float* __restrict__ a_src,
                                   const float* __restrict__ a_dst,
                                   int N) {
    __shared__ float sW[HO * 24];
    __shared__ float sAs[HO], sAd[HO];
    for (int i = threadIdx.x; i < HO * 24; i += blockDim.x) sW[i] = W[i];
    if (threadIdx.x < HO) {
        sAs[threadIdx.x] = a_src[threadIdx.x];
        sAd[threadIdx.x] = a_dst[threadIdx.x];
    }
    __syncthreads();
    int n = blockIdx.x * blockDim.x + threadIdx.x;
    if (n >= N) return;

    float yv[24];
    for (int k = 0; k < 24; ++k) yv[k] = x[n * 24 + k];

    float als[HEADS] = {0.f, 0.f, 0.f};
    float ald[HEADS] = {0.f, 0.f, 0.f};
    for (int ho = 0; ho < HO; ++ho) {
        float acc = 0.f;
        for (int k = 0; k < 24; ++k) acc += yv[k] * sW[ho * 24 + k];
        g_h[n * HO + ho] = acc;
        int hd = ho / OUT;
        als[hd] += acc * sAs[ho];
        ald[hd] += acc * sAd[ho];
    }
    for (int hd = 0; hd < HEADS; ++hd) {
        g_als[n * HEADS + hd] = als[hd];
        g_ald[n * HEADS + hd] = ald[hd];
    }
}

// ---------------- transform (layers 1-3, F=36): h = g_y @ W^T, logits ---
__global__ void transform36_kernel(const float* __restrict__ W,     // [36,36]
                                   const float* __restrict__ a_src,
                                   const float* __restrict__ a_dst,
                                   int N) {
    __shared__ float sW[HO * 36];
    __shared__ float sAs[HO], sAd[HO];
    for (int i = threadIdx.x; i < HO * 36; i += blockDim.x) sW[i] = W[i];
    if (threadIdx.x < HO) {
        sAs[threadIdx.x] = a_src[threadIdx.x];
        sAd[threadIdx.x] = a_dst[threadIdx.x];
    }
    __syncthreads();
    int n = blockIdx.x * blockDim.x + threadIdx.x;
    if (n >= N) return;

    float yv[36];
    for (int k = 0; k < 36; ++k) yv[k] = g_y[n * 36 + k];

    float als[HEADS] = {0.f, 0.f, 0.f};
    float ald[HEADS] = {0.f, 0.f, 0.f};
    for (int ho = 0; ho < HO; ++ho) {
        float acc = 0.f;
        for (int k = 0; k < 36; ++k) acc += yv[k] * sW[ho * 36 + k];
        g_h[n * HO + ho] = acc;
        int hd = ho / OUT;
        als[hd] += acc * sAs[ho];
        ald[hd] += acc * sAd[ho];
    }
    for (int hd = 0; hd < HEADS; ++hd) {
        g_als[n * HEADS + hd] = als[hd];
        g_ald[n * HEADS + hd] = ald[hd];
    }
}

// ---------------- gather (float4, 4-way unroll, degree-sorted) ----------
// 9 threads per node; thread q handles features [q*4, q*4+4). Nodes are
// processed in degree-sorted order (g_perm) so the ~7 nodes sharing a wave
// have equal trip counts (no divergence waste). 4 edges per iteration give
// 4 independent elist->als/h load chains (MLP vs the latency bound).
__global__ void gather_kernel(const float* __restrict__ bias, int N,
                              int relu_mode) {
    int t = blockIdx.x * blockDim.x + threadIdx.x;
    if (t >= N * 9) return;
    int n = g_perm[t / 9];
    int q = t - (t / 9) * 9;      // float4 index within the 36 features
    int hd = q / 3;               // head = (q*4)/12
    float ald = g_ald[n * HEADS + hd];
    int beg = g_off[n];
    int end = beg + g_deg[n];
    float4 acc = {0.f, 0.f, 0.f, 0.f};
    float wsum = 0.f;
    int s = beg;
    for (; s + 3 < end; s += 4) {
        int s0 = g_elist[s + 0], s1 = g_elist[s + 1];
        int s2 = g_elist[s + 2], s3 = g_elist[s + 3];
        float e0 = g_als[s0 * HEADS + hd] + ald;
        float e1 = g_als[s1 * HEADS + hd] + ald;
        float e2 = g_als[s2 * HEADS + hd] + ald;
        float e3 = g_als[s3 * HEADS + hd] + ald;
        float4 h0 = *(const float4*)(g_h + (size_t)s0 * HO + q * 4);
        float4 h1 = *(const float4*)(g_h + (size_t)s1 * HO + q * 4);
        float4 h2 = *(const float4*)(g_h + (size_t)s2 * HO + q * 4);
        float4 h3 = *(const float4*)(g_h + (size_t)s3 * HO + q * 4);
        e0 = (e0 > 0.f) ? e0 : 0.2f * e0;
        e1 = (e1 > 0.f) ? e1 : 0.2f * e1;
        e2 = (e2 > 0.f) ? e2 : 0.2f * e2;
        e3 = (e3 > 0.f) ? e3 : 0.2f * e3;
        float w0 = __expf(e0), w1 = __expf(e1);
        float w2 = __expf(e2), w3 = __expf(e3);
        wsum += (w0 + w1) + (w2 + w3);
        acc.x += w0 * h0.x + w1 * h1.x + w2 * h2.x + w3 * h3.x;
        acc.y += w0 * h0.y + w1 * h1.y + w2 * h2.y + w3 * h3.y;
        acc.z += w0 * h0.z + w1 * h1.z + w2 * h2.z + w3 * h3.z;
        acc.w += w0 * h0.w + w1 * h1.w + w2 * h2.w + w3 * h3.w;
    }
    for (; s < end; ++s) {
        int src = g_elist[s];
        float e = g_als[src * HEADS + hd] + ald;
        e = (e > 0.f) ? e : 0.2f * e;
        float w = __expf(e);
        wsum += w;
        float4 hv = *(const float4*)(g_h + (size_t)src * HO + q * 4);
        acc.x += w * hv.x; acc.y += w * hv.y;
        acc.z += w * hv.z; acc.w += w * hv.w;
    }
    float inv = 1.f / (wsum + 1e-16f);
    float4 v = {acc.x * inv, acc.y * inv, acc.z * inv, acc.w * inv};
    if (relu_mode) {
        v.x += bias[q * 4 + 0]; v.y += bias[q * 4 + 1];
        v.z += bias[q * 4 + 2]; v.w += bias[q * 4 + 3];
        v.x = v.x > 0.f ? v.x : 0.f; v.y = v.y > 0.f ? v.y : 0.f;
        v.z = v.z > 0.f ? v.z : 0.f; v.w = v.w > 0.f ? v.w : 0.f;
    }
    *(float4*)(g_y + (size_t)n * HO + q * 4) = v;
}

// ---------------- layer-3 epilogue: mean heads + b3 + lin1 + lin2 -------
__global__ void finalize3_kernel(const float* __restrict__ b3,     // [12]
                                 const float* __restrict__ lin1_w, // [12,12]
                                 const float* __restrict__ lin1_b, // [12]
                                 const float* __restrict__ lin2_w, // [6,12]
                                 const float* __restrict__ lin2_b, // [6]
                                 float* __restrict__ out,          // [N,6]
                                 int N) {
    __shared__ float sl1[144], sl2[72], sl1b[12], sl2b[6], sb3[12];
    if (threadIdx.x < 144) sl1[threadIdx.x] = lin1_w[threadIdx.x];
    if (threadIdx.x < 72)  sl2[threadIdx.x] = lin2_w[threadIdx.x];
    if (threadIdx.x < 12)  { sl1b[threadIdx.x] = lin1_b[threadIdx.x]; sb3[threadIdx.x] = b3[threadIdx.x]; }
    if (threadIdx.x < 6)   sl2b[threadIdx.x] = lin2_b[threadIdx.x];
    __syncthreads();
    int n = blockIdx.x * blockDim.x + threadIdx.x;
    if (n >= N) return;

    float v[12];
    for (int o = 0; o < OUT; ++o) {
        float acc = 0.f;
        for (int hd = 0; hd < HEADS; ++hd)
            acc += g_y[n * HO + hd * OUT + o];
        v[o] = acc * (1.f / 3.f) + sb3[o];
    }
    float t1[12];
    for (int i = 0; i < 12; ++i) {
        float acc = sl1b[i];
        for (int o = 0; o < 12; ++o) acc += v[o] * sl1[i * 12 + o];
        t1[i] = acc;
    }
    for (int j = 0; j < 6; ++j) {
        float acc = sl2b[j];
        for (int i = 0; i < 12; ++i) acc += t1[i] * sl2[j * 12 + i];
        out[n * 6 + j] = acc;
    }
}

extern "C" void kernel_launch(void* const* d_in, const int* in_sizes, int n_in,
                              void* d_out, int out_size, void* d_ws, size_t ws_size,
                              hipStream_t stream) {
    if (n_in < 22 || d_out == nullptr) return;  // fail readably, not fatally

    const float* x  = (const float*)d_in[0];
    const int*   ei = (const int*)d_in[1];
    int N = in_sizes[0] / 24;   // 50000
    int E = in_sizes[1] / 2;    // 800000
    if (N > NMAX) N = NMAX;
    if (E + N > EMAX) E = EMAX - N;

    const float* W0  = (const float*)d_in[2];
    const float* As0 = (const float*)d_in[3];
    const float* Ad0 = (const float*)d_in[4];
    const float* B0  = (const float*)d_in[5];
    const float* W1  = (const float*)d_in[6];
    const float* As1 = (const float*)d_in[7];
    const float* Ad1 = (const float*)d_in[8];
    const float* B1  = (const float*)d_in[9];
    const float* W2  = (const float*)d_in[10];
    const float* As2 = (const float*)d_in[11];
    const float* Ad2 = (const float*)d_in[12];
    const float* B2  = (const float*)d_in[13];
    const float* W3  = (const float*)d_in[14];
    const float* As3 = (const float*)d_in[15];
    const float* Ad3 = (const float*)d_in[16];
    const float* B3  = (const float*)d_in[17];
    const float* lin1_w = (const float*)d_in[18];
    const float* lin1_b = (const float*)d_in[19];
    const float* lin2_w = (const float*)d_in[20];
    const float* lin2_b = (const float*)d_in[21];
    float* out = (float*)d_out;

    const int BLK = 256;
    const int nodeBlocks = (N + BLK - 1) / BLK;
    const int edgeBlocks = (E + N + BLK - 1) / BLK;
    const int gatherBlocks = (N * 9 + BLK - 1) / BLK;

    // ---- CSR build + degree sort, once per call ----
    csr_zero_kernel<<<nodeBlocks, BLK, 0, stream>>>(N);
    csr_hist_kernel<<<edgeBlocks, BLK, 0, stream>>>(ei, E, N);
    csr_alloc_kernel<<<nodeBlocks, BLK, 0, stream>>>(N);
    csr_scatter_kernel<<<edgeBlocks, BLK, 0, stream>>>(ei, E, N);
    deg_hist_kernel<<<nodeBlocks, BLK, 0, stream>>>(N);
    deg_scan_kernel<<<1, 256, 0, stream>>>();
    deg_perm_kernel<<<nodeBlocks, BLK, 0, stream>>>(N);

    // ---- layer 0 ----
    transform24_kernel<<<nodeBlocks, BLK, 0, stream>>>(x, W0, As0, Ad0, N);
    gather_kernel<<<gatherBlocks, BLK, 0, stream>>>(B0, N, 1);
    // ---- layer 1 ----
    transform36_kernel<<<nodeBlocks, BLK, 0, stream>>>(W1, As1, Ad1, N);
    gather_kernel<<<gatherBlocks, BLK, 0, stream>>>(B1, N, 1);
    // ---- layer 2 ----
    transform36_kernel<<<nodeBlocks, BLK, 0, stream>>>(W2, As2, Ad2, N);
    gather_kernel<<<gatherBlocks, BLK, 0, stream>>>(B2, N, 1);
    // ---- layer 3 + head MLP ----
    transform36_kernel<<<nodeBlocks, BLK, 0, stream>>>(W3, As3, Ad3, N);
    gather_kernel<<<gatherBlocks, BLK, 0, stream>>>(B3, N, 0);
    finalize3_kernel<<<nodeBlocks, BLK, 0, stream>>>(
        B3, lin1_w, lin1_b, lin2_w, lin2_b, out, N);
}

// Round 9
// 372.341 us; speedup vs baseline: 1.6927x; 1.6927x over previous
//
#include <hip/hip_runtime.h>

#define HEADS 3
#define OUT   12
#define HO    36     // HEADS*OUT
#define NMAX  50000
#define EMAX  900000  // E + N self-loops = 850000 for this problem

// Static device-global scratch (no ws_size dependency, no runtime API).
__device__ __align__(16) float g_h  [NMAX * HO];     // transformed features
__device__ __align__(16) float g_als[NMAX * HEADS];  // src attention logits
__device__ __align__(16) float g_ald[NMAX * HEADS];  // dst attention logits
__device__ __align__(16) float g_y  [NMAX * HO];     // layer output
__device__ int g_deg [NMAX];       // in-degree histogram
__device__ int g_off [NMAX];       // CSR row starts (arbitrary order, contiguous per row)
__device__ int g_pos [NMAX];       // scatter cursors
__device__ int g_elist[EMAX];      // CSR: src node per slot
__device__ int g_cursor;           // row allocation cursor

// ---------------- CSR build (rebuilt every call; graph is an input) ------
__global__ void csr_zero_kernel(int N) {
    int t = blockIdx.x * blockDim.x + threadIdx.x;
    if (t < N) { g_deg[t] = 0; g_pos[t] = 0; }
    if (t == 0) g_cursor = 0;
}

__global__ void csr_hist_kernel(const int* __restrict__ ei, int E, int N) {
    int t = blockIdx.x * blockDim.x + threadIdx.x;
    if (t >= E + N) return;
    int dst = (t < E) ? ei[E + t] : (t - E);   // explicit edges + self-loops
    atomicAdd(&g_deg[dst], 1);
}

// Scan-free row allocation: rows contiguous but in arbitrary order, which is
// all the gather needs. (NOTE: R8 showed counting-sort style binning onto
// <=256 bins via global atomics costs >200us from same-address serialization
// — do not reintroduce a degree sort that way.)
__global__ void csr_alloc_kernel(int N) {
    int n = blockIdx.x * blockDim.x + threadIdx.x;
    if (n >= N) return;
    g_off[n] = atomicAdd(&g_cursor, g_deg[n]);
}

__global__ void csr_scatter_kernel(const int* __restrict__ ei, int E, int N) {
    int t = blockIdx.x * blockDim.x + threadIdx.x;
    if (t >= E + N) return;
    int src, dst;
    if (t < E) { src = ei[t]; dst = ei[E + t]; }
    else       { src = dst = t - E; }
    int slot = g_off[dst] + atomicAdd(&g_pos[dst], 1);
    g_elist[slot] = src;
}

// ---------------- transform (layer 0, F=24): h = x @ W^T, logits --------
__global__ void transform24_kernel(const float* __restrict__ x,
                                   const float* __restrict__ W,     // [36,24]
                                   const float* __restrict__ a_src,
                                   const float* __restrict__ a_dst,
                                   int N) {
    __shared__ float sW[HO * 24];
    __shared__ float sAs[HO], sAd[HO];
    for (int i = threadIdx.x; i < HO * 24; i += blockDim.x) sW[i] = W[i];
    if (threadIdx.x < HO) {
        sAs[threadIdx.x] = a_src[threadIdx.x];
        sAd[threadIdx.x] = a_dst[threadIdx.x];
    }
    __syncthreads();
    int n = blockIdx.x * blockDim.x + threadIdx.x;
    if (n >= N) return;

    float yv[24];
    for (int k = 0; k < 24; ++k) yv[k] = x[n * 24 + k];

    float als[HEADS] = {0.f, 0.f, 0.f};
    float ald[HEADS] = {0.f, 0.f, 0.f};
    for (int ho = 0; ho < HO; ++ho) {
        float acc = 0.f;
        for (int k = 0; k < 24; ++k) acc += yv[k] * sW[ho * 24 + k];
        g_h[n * HO + ho] = acc;
        int hd = ho / OUT;
        als[hd] += acc * sAs[ho];
        ald[hd] += acc * sAd[ho];
    }
    for (int hd = 0; hd < HEADS; ++hd) {
        g_als[n * HEADS + hd] = als[hd];
        g_ald[n * HEADS + hd] = ald[hd];
    }
}

// ---------------- transform (layers 1-3, F=36): h = g_y @ W^T, logits ---
__global__ void transform36_kernel(const float* __restrict__ W,     // [36,36]
                                   const float* __restrict__ a_src,
                                   const float* __restrict__ a_dst,
                                   int N) {
    __shared__ float sW[HO * 36];
    __shared__ float sAs[HO], sAd[HO];
    for (int i = threadIdx.x; i < HO * 36; i += blockDim.x) sW[i] = W[i];
    if (threadIdx.x < HO) {
        sAs[threadIdx.x] = a_src[threadIdx.x];
        sAd[threadIdx.x] = a_dst[threadIdx.x];
    }
    __syncthreads();
    int n = blockIdx.x * blockDim.x + threadIdx.x;
    if (n >= N) return;

    float yv[36];
    for (int k = 0; k < 36; ++k) yv[k] = g_y[n * 36 + k];

    float als[HEADS] = {0.f, 0.f, 0.f};
    float ald[HEADS] = {0.f, 0.f, 0.f};
    for (int ho = 0; ho < HO; ++ho) {
        float acc = 0.f;
        for (int k = 0; k < 36; ++k) acc += yv[k] * sW[ho * 36 + k];
        g_h[n * HO + ho] = acc;
        int hd = ho / OUT;
        als[hd] += acc * sAs[ho];
        ald[hd] += acc * sAd[ho];
    }
    for (int hd = 0; hd < HEADS; ++hd) {
        g_als[n * HEADS + hd] = als[hd];
        g_ald[n * HEADS + hd] = ald[hd];
    }
}

// ---------------- gather (float4, 4-way unroll) -------------------------
// 9 threads per node; thread q handles features [q*4, q*4+4). The 9 lanes of
// one node load a contiguous 144B chunk of g_h per edge (coalesced). 4 edges
// per iteration give 4 independent elist->als/h load chains (MLP vs latency).
// Natural node order: g_y writes stay fully coalesced.
__global__ void gather_kernel(const float* __restrict__ bias, int N,
                              int relu_mode) {
    int t = blockIdx.x * blockDim.x + threadIdx.x;
    if (t >= N * 9) return;
    int n = t / 9;
    int q = t - n * 9;            // float4 index within the 36 features
    int hd = q / 3;               // head = (q*4)/12
    float ald = g_ald[n * HEADS + hd];
    int beg = g_off[n];
    int end = beg + g_deg[n];
    float4 acc = {0.f, 0.f, 0.f, 0.f};
    float wsum = 0.f;
    int s = beg;
    for (; s + 3 < end; s += 4) {
        int s0 = g_elist[s + 0], s1 = g_elist[s + 1];
        int s2 = g_elist[s + 2], s3 = g_elist[s + 3];
        float e0 = g_als[s0 * HEADS + hd] + ald;
        float e1 = g_als[s1 * HEADS + hd] + ald;
        float e2 = g_als[s2 * HEADS + hd] + ald;
        float e3 = g_als[s3 * HEADS + hd] + ald;
        float4 h0 = *(const float4*)(g_h + (size_t)s0 * HO + q * 4);
        float4 h1 = *(const float4*)(g_h + (size_t)s1 * HO + q * 4);
        float4 h2 = *(const float4*)(g_h + (size_t)s2 * HO + q * 4);
        float4 h3 = *(const float4*)(g_h + (size_t)s3 * HO + q * 4);
        e0 = (e0 > 0.f) ? e0 : 0.2f * e0;
        e1 = (e1 > 0.f) ? e1 : 0.2f * e1;
        e2 = (e2 > 0.f) ? e2 : 0.2f * e2;
        e3 = (e3 > 0.f) ? e3 : 0.2f * e3;
        float w0 = __expf(e0), w1 = __expf(e1);
        float w2 = __expf(e2), w3 = __expf(e3);
        wsum += (w0 + w1) + (w2 + w3);
        acc.x += w0 * h0.x + w1 * h1.x + w2 * h2.x + w3 * h3.x;
        acc.y += w0 * h0.y + w1 * h1.y + w2 * h2.y + w3 * h3.y;
        acc.z += w0 * h0.z + w1 * h1.z + w2 * h2.z + w3 * h3.z;
        acc.w += w0 * h0.w + w1 * h1.w + w2 * h2.w + w3 * h3.w;
    }
    for (; s < end; ++s) {
        int src = g_elist[s];
        float e = g_als[src * HEADS + hd] + ald;
        e = (e > 0.f) ? e : 0.2f * e;
        float w = __expf(e);
        wsum += w;
        float4 hv = *(const float4*)(g_h + (size_t)src * HO + q * 4);
        acc.x += w * hv.x; acc.y += w * hv.y;
        acc.z += w * hv.z; acc.w += w * hv.w;
    }
    float inv = 1.f / (wsum + 1e-16f);
    float4 v = {acc.x * inv, acc.y * inv, acc.z * inv, acc.w * inv};
    if (relu_mode) {
        v.x += bias[q * 4 + 0]; v.y += bias[q * 4 + 1];
        v.z += bias[q * 4 + 2]; v.w += bias[q * 4 + 3];
        v.x = v.x > 0.f ? v.x : 0.f; v.y = v.y > 0.f ? v.y : 0.f;
        v.z = v.z > 0.f ? v.z : 0.f; v.w = v.w > 0.f ? v.w : 0.f;
    }
    *(float4*)(g_y + (size_t)n * HO + q * 4) = v;
}

// ---------------- layer-3 epilogue: mean heads + b3 + lin1 + lin2 -------
__global__ void finalize3_kernel(const float* __restrict__ b3,     // [12]
                                 const float* __restrict__ lin1_w, // [12,12]
                                 const float* __restrict__ lin1_b, // [12]
                                 const float* __restrict__ lin2_w, // [6,12]
                                 const float* __restrict__ lin2_b, // [6]
                                 float* __restrict__ out,          // [N,6]
                                 int N) {
    __shared__ float sl1[144], sl2[72], sl1b[12], sl2b[6], sb3[12];
    if (threadIdx.x < 144) sl1[threadIdx.x] = lin1_w[threadIdx.x];
    if (threadIdx.x < 72)  sl2[threadIdx.x] = lin2_w[threadIdx.x];
    if (threadIdx.x < 12)  { sl1b[threadIdx.x] = lin1_b[threadIdx.x]; sb3[threadIdx.x] = b3[threadIdx.x]; }
    if (threadIdx.x < 6)   sl2b[threadIdx.x] = lin2_b[threadIdx.x];
    __syncthreads();
    int n = blockIdx.x * blockDim.x + threadIdx.x;
    if (n >= N) return;

    float v[12];
    for (int o = 0; o < OUT; ++o) {
        float acc = 0.f;
        for (int hd = 0; hd < HEADS; ++hd)
            acc += g_y[n * HO + hd * OUT + o];
        v[o] = acc * (1.f / 3.f) + sb3[o];
    }
    float t1[12];
    for (int i = 0; i < 12; ++i) {
        float acc = sl1b[i];
        for (int o = 0; o < 12; ++o) acc += v[o] * sl1[i * 12 + o];
        t1[i] = acc;
    }
    for (int j = 0; j < 6; ++j) {
        float acc = sl2b[j];
        for (int i = 0; i < 12; ++i) acc += t1[i] * sl2[j * 12 + i];
        out[n * 6 + j] = acc;
    }
}

extern "C" void kernel_launch(void* const* d_in, const int* in_sizes, int n_in,
                              void* d_out, int out_size, void* d_ws, size_t ws_size,
                              hipStream_t stream) {
    if (n_in < 22 || d_out == nullptr) return;  // fail readably, not fatally

    const float* x  = (const float*)d_in[0];
    const int*   ei = (const int*)d_in[1];
    int N = in_sizes[0] / 24;   // 50000
    int E = in_sizes[1] / 2;    // 800000
    if (N > NMAX) N = NMAX;
    if (E + N > EMAX) E = EMAX - N;

    const float* W0  = (const float*)d_in[2];
    const float* As0 = (const float*)d_in[3];
    const float* Ad0 = (const float*)d_in[4];
    const float* B0  = (const float*)d_in[5];
    const float* W1  = (const float*)d_in[6];
    const float* As1 = (const float*)d_in[7];
    const float* Ad1 = (const float*)d_in[8];
    const float* B1  = (const float*)d_in[9];
    const float* W2  = (const float*)d_in[10];
    const float* As2 = (const float*)d_in[11];
    const float* Ad2 = (const float*)d_in[12];
    const float* B2  = (const float*)d_in[13];
    const float* W3  = (const float*)d_in[14];
    const float* As3 = (const float*)d_in[15];
    const float* Ad3 = (const float*)d_in[16];
    const float* B3  = (const float*)d_in[17];
    const float* lin1_w = (const float*)d_in[18];
    const float* lin1_b = (const float*)d_in[19];
    const float* lin2_w = (const float*)d_in[20];
    const float* lin2_b = (const float*)d_in[21];
    float* out = (float*)d_out;

    const int BLK = 256;
    const int nodeBlocks = (N + BLK - 1) / BLK;
    const int edgeBlocks = (E + N + BLK - 1) / BLK;
    const int gatherBlocks = (N * 9 + BLK - 1) / BLK;

    // ---- CSR build (by dst, rows in arbitrary order), once per call ----
    csr_zero_kernel<<<nodeBlocks, BLK, 0, stream>>>(N);
    csr_hist_kernel<<<edgeBlocks, BLK, 0, stream>>>(ei, E, N);
    csr_alloc_kernel<<<nodeBlocks, BLK, 0, stream>>>(N);
    csr_scatter_kernel<<<edgeBlocks, BLK, 0, stream>>>(ei, E, N);

    // ---- layer 0 ----
    transform24_kernel<<<nodeBlocks, BLK, 0, stream>>>(x, W0, As0, Ad0, N);
    gather_kernel<<<gatherBlocks, BLK, 0, stream>>>(B0, N, 1);
    // ---- layer 1 ----
    transform36_kernel<<<nodeBlocks, BLK, 0, stream>>>(W1, As1, Ad1, N);
    gather_kernel<<<gatherBlocks, BLK, 0, stream>>>(B1, N, 1);
    // ---- layer 2 ----
    transform36_kernel<<<nodeBlocks, BLK, 0, stream>>>(W2, As2, Ad2, N);
    gather_kernel<<<gatherBlocks, BLK, 0, stream>>>(B2, N, 1);
    // ---- layer 3 + head MLP ----
    transform36_kernel<<<nodeBlocks, BLK, 0, stream>>>(W3, As3, Ad3, N);
    gather_kernel<<<gatherBlocks, BLK, 0, stream>>>(B3, N, 0);
    finalize3_kernel<<<nodeBlocks, BLK, 0, stream>>>(
        B3, lin1_w, lin1_b, lin2_w, lin2_b, out, N);
}